// Round 2
// baseline (2795.703 us; speedup 1.0000x reference)
//
#include <hip/hip_runtime.h>
#include <stdint.h>

#define GRAPHS 256
#define NPG    512
#define EPG    8192
#define NTOT   (GRAPHS*NPG)

typedef __attribute__((ext_vector_type(8))) short s16x8;
typedef __attribute__((ext_vector_type(4))) float f32x4;

__device__ __forceinline__ float bf2f(unsigned short u){
  union { unsigned int i; float f; } c; c.i = ((unsigned int)u)<<16; return c.f;
}
__device__ __forceinline__ unsigned short f2bf(float f){
  union { float f; unsigned int i; } c; c.f = f;
  unsigned int r = c.i + 0x7fffu + ((c.i>>16)&1u);   // RNE
  return (unsigned short)(r>>16);
}

// ---------------- degrees -> isqrt ----------------
__global__ __launch_bounds__(256) void k_deg(const int* __restrict__ src,
      const int* __restrict__ dst, float* __restrict__ out_isqrt,
      float* __restrict__ in_isqrt){
  __shared__ int co[NPG], ci[NPG];
  const int b = blockIdx.x, tid = threadIdx.x;
  co[tid]=0; co[tid+256]=0; ci[tid]=0; ci[tid+256]=0;
  __syncthreads();
  const int base = b*EPG;
  for (int i=tid;i<EPG;i+=256){
    atomicAdd(&co[src[base+i]&(NPG-1)],1);
    atomicAdd(&ci[dst[base+i]&(NPG-1)],1);
  }
  __syncthreads();
  const int nb = b*NPG;
  for (int v=tid;v<NPG;v+=256){
    int a = co[v]; if (a<1) a=1;
    int c = ci[v]; if (c<1) c=1;
    out_isqrt[nb+v] = rsqrtf((float)a);
    in_isqrt[nb+v]  = rsqrtf((float)c);
  }
}

// ---------------- aggregation (one block = one graph x one 64-col half) -----
// LAYER 1: source row j -> emb[type[src]][half*64 + j]   (fp32)
// LAYER 2: source row j -> h[half][src][j]               (bf16, split-half)
// Output: aggO[half][node][j] = in_isqrt[node] * sum_{e:dst=node} out_isqrt[src]*h_src[j]
template<int LAYER>
__global__ __launch_bounds__(512) void k_agg(const int* __restrict__ src,
      const int* __restrict__ dst, const int* __restrict__ ntype,
      const float* __restrict__ emb, const unsigned short* __restrict__ h,
      const float* __restrict__ out_isqrt, const float* __restrict__ in_isqrt,
      unsigned short* __restrict__ aggO){
  extern __shared__ float lds[];            // NPG * 65 floats (pad 65: bank spread)
  const int b    = blockIdx.x >> 1;
  const int half = blockIdx.x & 1;
  const int tid  = threadIdx.x;
  for (int i=tid;i<NPG*65;i+=512) lds[i]=0.f;
  __syncthreads();
  const int l16 = tid & 15, grp = tid >> 4;          // 32 edge groups of 16 lanes
  const int ebase = b*EPG;
  #pragma unroll 2
  for (int it=0; it<EPG/32; ++it){
    const int e  = ebase + it*32 + grp;
    const int s  = src[e];
    const int dl = dst[e] & (NPG-1);
    const float w = out_isqrt[s];
    float v0,v1,v2,v3;
    if (LAYER==1){
      const float* hs = emb + (ntype[s]<<7) + (half<<6) + (l16<<2);
      float4 q = *(const float4*)hs;                  // 16B
      v0=q.x; v1=q.y; v2=q.z; v3=q.w;
    } else {
      const unsigned short* hp = h + ((size_t)half*NTOT + (size_t)s)*64 + (l16<<2);
      ushort4 q = *(const ushort4*)hp;                // 8B
      v0=bf2f(q.x); v1=bf2f(q.y); v2=bf2f(q.z); v3=bf2f(q.w);
    }
    const int ad = dl*65 + (l16<<2);
    atomicAdd(&lds[ad+0], w*v0);
    atomicAdd(&lds[ad+1], w*v1);
    atomicAdd(&lds[ad+2], w*v2);
    atomicAdd(&lds[ad+3], w*v3);
  }
  __syncthreads();
  unsigned short* o = aggO + (size_t)half*NTOT*64 + (size_t)b*NPG*64;
  const int nb = b*NPG;
  for (int i=tid; i<NPG*32; i+=512){
    const int v = i>>5, jj = (i&31)<<1;
    const float sc = in_isqrt[nb + v];
    unsigned int pack = ((unsigned int)f2bf(lds[v*65+jj+1]*sc)<<16)
                      |  (unsigned int)f2bf(lds[v*65+jj  ]*sc);
    *(unsigned int*)(o + v*64 + jj) = pack;
  }
}

// ---------------- GEMM: [512,128] @ [128,128] + bias, relu ------------------
// A in split-half layout [2][NTOT][64] bf16. W fp32 [k][n] row-major -> bf16 LDS.
// LAYER 1: store h1 (split-half bf16). LAYER 2: fused per-graph mean -> out[b][c] fp32.
template<int LAYER>
__global__ __launch_bounds__(256) void k_gemm(const unsigned short* __restrict__ A,
      const float* __restrict__ W, const float* __restrict__ bias,
      void* __restrict__ outv){
  __shared__ __align__(16) unsigned short WT[128][136];  // WT[n][k], pad 136
  __shared__ float bsh[128];
  __shared__ float colpart[4][128];
  const int b = blockIdx.x, tid = threadIdx.x;
  for (int idx=tid; idx<128*128; idx+=256){
    const int k = idx>>7, n = idx&127;
    WT[n][k] = f2bf(W[idx]);
  }
  if (tid<128) bsh[tid] = bias[tid];
  __syncthreads();
  const int wave = tid>>6, lane = tid&63;
  const int l16 = lane&15, quad = lane>>4;
  float p[8];
  #pragma unroll
  for (int i=0;i<8;i++) p[i]=0.f;

  for (int chunk=0; chunk<4; ++chunk){
    const int rowbase = b*NPG + wave*128 + chunk*32;
    f32x4 acc[2][8];
    #pragma unroll
    for (int rt=0; rt<2; ++rt)
      #pragma unroll
      for (int ct=0; ct<8; ++ct)
        acc[rt][ct] = (f32x4){0.f,0.f,0.f,0.f};

    #pragma unroll
    for (int ks=0; ks<4; ++ks){
      s16x8 a[2], bf[8];
      #pragma unroll
      for (int rt=0; rt<2; ++rt){
        const unsigned short* ap = A + (size_t)(ks>>1)*NTOT*64
            + (size_t)(rowbase + rt*16 + l16)*64 + (ks&1)*32 + quad*8;
        a[rt] = __builtin_bit_cast(s16x8, *(const uint4*)ap);
      }
      #pragma unroll
      for (int ct=0; ct<8; ++ct)
        bf[ct] = __builtin_bit_cast(s16x8, *(const uint4*)&WT[ct*16+l16][ks*32+quad*8]);
      #pragma unroll
      for (int rt=0; rt<2; ++rt)
        #pragma unroll
        for (int ct=0; ct<8; ++ct)
          acc[rt][ct] = __builtin_amdgcn_mfma_f32_16x16x32_bf16(a[rt], bf[ct], acc[rt][ct], 0,0,0);
    }
    #pragma unroll
    for (int rt=0; rt<2; ++rt)
      #pragma unroll
      for (int ct=0; ct<8; ++ct)
        #pragma unroll
        for (int r=0; r<4; ++r){
          const int col = ct*16 + l16;
          float v = acc[rt][ct][r] + bsh[col];
          v = fmaxf(v, 0.f);
          if (LAYER==1){
            unsigned short* out = (unsigned short*)outv;
            const int row = rowbase + rt*16 + quad*4 + r;
            out[(size_t)(ct>>2)*NTOT*64 + (size_t)row*64 + (ct&3)*16 + l16] = f2bf(v);
          } else {
            p[ct] += v;
          }
        }
  }
  if (LAYER==2){
    float* out = (float*)outv;
    #pragma unroll
    for (int ct=0;ct<8;ct++){
      p[ct] += __shfl_xor(p[ct], 16);
      p[ct] += __shfl_xor(p[ct], 32);
    }
    if (quad==0){
      #pragma unroll
      for (int ct=0;ct<8;ct++) colpart[wave][ct*16+l16] = p[ct];
    }
    __syncthreads();
    if (tid<128){
      float s = colpart[0][tid]+colpart[1][tid]+colpart[2][tid]+colpart[3][tid];
      out[b*128 + tid] = s * (1.f/512.f);
    }
  }
}

extern "C" void kernel_launch(void* const* d_in, const int* in_sizes, int n_in,
                              void* d_out, int out_size, void* d_ws, size_t ws_size,
                              hipStream_t stream){
  const int* node_feat = (const int*)d_in[0];
  const int* src = (const int*)d_in[1];
  const int* dst = (const int*)d_in[2];
  const float* emb = (const float*)d_in[3];
  const float* W1  = (const float*)d_in[4];
  const float* b1  = (const float*)d_in[5];
  const float* W2  = (const float*)d_in[6];
  const float* b2  = (const float*)d_in[7];

  char* ws = (char*)d_ws;
  float* out_isqrt = (float*)(ws);
  float* in_isqrt  = (float*)(ws + (size_t)NTOT*4);
  unsigned short* aggG = (unsigned short*)(ws + (size_t)NTOT*8);
  unsigned short* h1   = (unsigned short*)(ws + (size_t)NTOT*8 + (size_t)NTOT*128*2);

  const int ldsBytes = NPG*65*4;   // 133120 B dynamic LDS (gfx950: 160KB/CU)
  (void)hipFuncSetAttribute(reinterpret_cast<const void*>(&k_agg<1>),
        hipFuncAttributeMaxDynamicSharedMemorySize, ldsBytes);
  (void)hipFuncSetAttribute(reinterpret_cast<const void*>(&k_agg<2>),
        hipFuncAttributeMaxDynamicSharedMemorySize, ldsBytes);

  k_deg<<<GRAPHS,256,0,stream>>>(src,dst,out_isqrt,in_isqrt);
  k_agg<1><<<GRAPHS*2,512,ldsBytes,stream>>>(src,dst,node_feat,emb,
        (const unsigned short*)nullptr,out_isqrt,in_isqrt,aggG);
  k_gemm<1><<<GRAPHS,256,0,stream>>>(aggG,W1,b1,(void*)h1);
  k_agg<2><<<GRAPHS*2,512,ldsBytes,stream>>>(src,dst,node_feat,emb,h1,
        out_isqrt,in_isqrt,aggG);
  k_gemm<2><<<GRAPHS,256,0,stream>>>(aggG,W2,b2,(void*)d_out);
}

// Round 3
// 297.603 us; speedup vs baseline: 9.3941x; 9.3941x over previous
//
#include <hip/hip_runtime.h>
#include <stdint.h>

#define GRAPHS 256
#define NPG    512
#define EPG    8192
#define NTOT   (GRAPHS*NPG)

typedef __attribute__((ext_vector_type(8))) short s16x8;
typedef __attribute__((ext_vector_type(4))) float f32x4;

__device__ __forceinline__ float bf2f(unsigned short u){
  union { unsigned int i; float f; } c; c.i = ((unsigned int)u)<<16; return c.f;
}
__device__ __forceinline__ unsigned short f2bf(float f){
  union { float f; unsigned int i; } c; c.f = f;
  unsigned int r = c.i + 0x7fffu + ((c.i>>16)&1u);   // RNE
  return (unsigned short)(r>>16);
}

// ---------------- degrees -> isqrt (out-degree needed globally) -------------
__global__ __launch_bounds__(256) void k_deg(const int* __restrict__ src,
      const int* __restrict__ dst, float* __restrict__ out_isqrt,
      float* __restrict__ in_isqrt){
  __shared__ int co[NPG], ci[NPG];
  const int b = blockIdx.x, tid = threadIdx.x;
  co[tid]=0; co[tid+256]=0; ci[tid]=0; ci[tid+256]=0;
  __syncthreads();
  const int base = b*EPG;
  for (int i=tid;i<EPG;i+=256){
    atomicAdd(&co[src[base+i]&(NPG-1)],1);
    atomicAdd(&ci[dst[base+i]&(NPG-1)],1);
  }
  __syncthreads();
  const int nb = b*NPG;
  for (int v=tid;v<NPG;v+=256){
    int a = co[v]; if (a<1) a=1;
    int c = ci[v]; if (c<1) c=1;
    out_isqrt[nb+v] = rsqrtf((float)a);
    in_isqrt[nb+v]  = rsqrtf((float)c);
  }
}

// ---------------- CSR aggregation (no float atomics) ------------------------
// One block = one graph x one 64-col half. 512 threads = 32 groups of 16.
// Phase A: counting-sort edges by dst into u16 sorted[] (L1 packs ntype<<9).
// Phase B: each group accumulates 16 dst nodes in registers from LDS-staged
//          features (L1: emb slice fp32; L2: h1 graph slice bf16).
#define SORTED_OFF 0        // u16[8192]            16384 B
#define START_OFF  16384    // int[513]              2056 B (padded)
#define CURSOR_OFF 18440    // int[512]              2048 B
#define WSC_OFF    20488    // float[512]            2048 B
#define NTYPE_OFF  22536    // int[512]              2048 B
#define FEAT_OFF   24592    // 16B aligned; L1: f32[64*68]=17408; L2: u16[512*68]=69632
#define LDS_L1     42000
#define LDS_L2     94224

template<int LAYER>
__global__ __launch_bounds__(512) void k_agg_csr(const int* __restrict__ src,
      const int* __restrict__ dst, const int* __restrict__ ntype,
      const float* __restrict__ emb, const unsigned short* __restrict__ h,
      const float* __restrict__ out_isqrt, unsigned short* __restrict__ aggO){
  extern __shared__ char smem[];
  unsigned short* sorted = (unsigned short*)(smem + SORTED_OFF);
  int*   cs_start = (int*)(smem + START_OFF);
  int*   cursor   = (int*)(smem + CURSOR_OFF);
  float* wsc      = (float*)(smem + WSC_OFF);
  int*   ntype_sh = (int*)(smem + NTYPE_OFF);

  const int b    = blockIdx.x >> 1;
  const int half = blockIdx.x & 1;
  const int tid  = threadIdx.x;
  const int nb   = b*NPG, eb = b*EPG;

  // ---- init + staging ----
  for (int v=tid; v<NPG; v+=512){
    cursor[v] = 0;
    wsc[v] = out_isqrt[nb+v];
    if (LAYER==1) ntype_sh[v] = ntype[nb+v];
  }
  if (LAYER==1){
    float* emb_sh = (float*)(smem + FEAT_OFF);
    for (int i=tid; i<64*64; i+=512){
      const int t = i>>6, c = i&63;
      emb_sh[t*68+c] = emb[(t<<7) + (half<<6) + c];
    }
  } else {
    unsigned short* h_sh = (unsigned short*)(smem + FEAT_OFF);
    for (int i=tid; i<8192; i+=512){
      const int v = i>>4, c = (i&15)<<2;
      *(ushort4*)&h_sh[v*68+c] =
          *(const ushort4*)&h[((size_t)half*NTOT + nb + v)*64 + c];
    }
  }
  __syncthreads();

  // ---- histogram of dst (int LDS atomics: native ds_add) ----
  int myd[16];
  #pragma unroll
  for (int k=0;k<16;k++){
    const int e = eb + k*512 + tid;
    const int dl = dst[e] & (NPG-1);
    myd[k] = dl;
    atomicAdd(&cursor[dl], 1);
  }
  __syncthreads();

  // ---- exclusive prefix scan (wave 0) ----
  if (tid < 64){
    int carry = 0;
    #pragma unroll
    for (int c=0;c<8;c++){
      int x = cursor[64*c + tid];
      int sc = x;
      #pragma unroll
      for (int off=1; off<64; off<<=1){
        int y = __shfl_up(sc, off);
        if (tid >= off) sc += y;
      }
      cs_start[64*c + tid + 1] = carry + sc;
      carry += __shfl(sc, 63);
    }
    if (tid==0) cs_start[0] = 0;
  }
  __syncthreads();
  for (int v=tid; v<NPG; v+=512) cursor[v] = cs_start[v];
  __syncthreads();

  // ---- scatter edges by dst ----
  #pragma unroll
  for (int k=0;k<16;k++){
    const int e = eb + k*512 + tid;
    const int s = src[e] & (NPG-1);
    const int pos = atomicAdd(&cursor[myd[k]], 1);
    unsigned short ent = (unsigned short)s;
    if (LAYER==1) ent |= (unsigned short)(ntype_sh[s] << 9);
    sorted[pos] = ent;
  }
  __syncthreads();

  // ---- per-node register accumulation ----
  const int g = tid >> 4, l = tid & 15;
  for (int vi=0; vi<16; ++vi){
    const int v   = g*16 + vi;
    const int beg = cs_start[v], end = cs_start[v+1];
    float a0=0.f, a1=0.f, a2=0.f, a3=0.f;
    int i = beg;
    if (LAYER==1){
      const float* emb_sh = (const float*)(smem + FEAT_OFF);
      for (; i+2<=end; i+=2){
        const int e0 = sorted[i], e1 = sorted[i+1];
        const float w0 = wsc[e0 & 511], w1 = wsc[e1 & 511];
        float4 q0 = *(const float4*)&emb_sh[(e0>>9)*68 + (l<<2)];
        float4 q1 = *(const float4*)&emb_sh[(e1>>9)*68 + (l<<2)];
        a0 += w0*q0.x; a1 += w0*q0.y; a2 += w0*q0.z; a3 += w0*q0.w;
        a0 += w1*q1.x; a1 += w1*q1.y; a2 += w1*q1.z; a3 += w1*q1.w;
      }
      if (i<end){
        const int e0 = sorted[i];
        const float w0 = wsc[e0 & 511];
        float4 q0 = *(const float4*)&emb_sh[(e0>>9)*68 + (l<<2)];
        a0 += w0*q0.x; a1 += w0*q0.y; a2 += w0*q0.z; a3 += w0*q0.w;
      }
    } else {
      const unsigned short* h_sh = (const unsigned short*)(smem + FEAT_OFF);
      for (; i+2<=end; i+=2){
        const int s0 = sorted[i], s1 = sorted[i+1];
        const float w0 = wsc[s0], w1 = wsc[s1];
        ushort4 q0 = *(const ushort4*)&h_sh[s0*68 + (l<<2)];
        ushort4 q1 = *(const ushort4*)&h_sh[s1*68 + (l<<2)];
        a0 += w0*bf2f(q0.x); a1 += w0*bf2f(q0.y); a2 += w0*bf2f(q0.z); a3 += w0*bf2f(q0.w);
        a0 += w1*bf2f(q1.x); a1 += w1*bf2f(q1.y); a2 += w1*bf2f(q1.z); a3 += w1*bf2f(q1.w);
      }
      if (i<end){
        const int s0 = sorted[i];
        const float w0 = wsc[s0];
        ushort4 q0 = *(const ushort4*)&h_sh[s0*68 + (l<<2)];
        a0 += w0*bf2f(q0.x); a1 += w0*bf2f(q0.y); a2 += w0*bf2f(q0.z); a3 += w0*bf2f(q0.w);
      }
    }
    int d = end - beg; if (d < 1) d = 1;
    const float isq = rsqrtf((float)d);
    ushort4 r;
    r.x = f2bf(a0*isq); r.y = f2bf(a1*isq); r.z = f2bf(a2*isq); r.w = f2bf(a3*isq);
    *(ushort4*)(aggO + ((size_t)half*NTOT + nb + v)*64 + (l<<2)) = r;
  }
}

// ---------------- GEMM: [512,128] @ [128,128] + bias, relu ------------------
// A in split-half layout [2][NTOT][64] bf16. W fp32 [k][n] row-major -> bf16 LDS.
// LAYER 1: store h1 (split-half bf16). LAYER 2: fused per-graph mean -> out[b][c] fp32.
template<int LAYER>
__global__ __launch_bounds__(256) void k_gemm(const unsigned short* __restrict__ A,
      const float* __restrict__ W, const float* __restrict__ bias,
      void* __restrict__ outv){
  __shared__ __align__(16) unsigned short WT[128][136];  // WT[n][k], pad 136
  __shared__ float bsh[128];
  __shared__ float colpart[4][128];
  const int b = blockIdx.x, tid = threadIdx.x;
  for (int idx=tid; idx<128*128; idx+=256){
    const int k = idx>>7, n = idx&127;
    WT[n][k] = f2bf(W[idx]);
  }
  if (tid<128) bsh[tid] = bias[tid];
  __syncthreads();
  const int wave = tid>>6, lane = tid&63;
  const int l16 = lane&15, quad = lane>>4;
  float p[8];
  #pragma unroll
  for (int i=0;i<8;i++) p[i]=0.f;

  for (int chunk=0; chunk<4; ++chunk){
    const int rowbase = b*NPG + wave*128 + chunk*32;
    f32x4 acc[2][8];
    #pragma unroll
    for (int rt=0; rt<2; ++rt)
      #pragma unroll
      for (int ct=0; ct<8; ++ct)
        acc[rt][ct] = (f32x4){0.f,0.f,0.f,0.f};

    #pragma unroll
    for (int ks=0; ks<4; ++ks){
      s16x8 a[2], bf[8];
      #pragma unroll
      for (int rt=0; rt<2; ++rt){
        const unsigned short* ap = A + (size_t)(ks>>1)*NTOT*64
            + (size_t)(rowbase + rt*16 + l16)*64 + (ks&1)*32 + quad*8;
        a[rt] = __builtin_bit_cast(s16x8, *(const uint4*)ap);
      }
      #pragma unroll
      for (int ct=0; ct<8; ++ct)
        bf[ct] = __builtin_bit_cast(s16x8, *(const uint4*)&WT[ct*16+l16][ks*32+quad*8]);
      #pragma unroll
      for (int rt=0; rt<2; ++rt)
        #pragma unroll
        for (int ct=0; ct<8; ++ct)
          acc[rt][ct] = __builtin_amdgcn_mfma_f32_16x16x32_bf16(a[rt], bf[ct], acc[rt][ct], 0,0,0);
    }
    #pragma unroll
    for (int rt=0; rt<2; ++rt)
      #pragma unroll
      for (int ct=0; ct<8; ++ct)
        #pragma unroll
        for (int r=0; r<4; ++r){
          const int col = ct*16 + l16;
          float v = acc[rt][ct][r] + bsh[col];
          v = fmaxf(v, 0.f);
          if (LAYER==1){
            unsigned short* out = (unsigned short*)outv;
            const int row = rowbase + rt*16 + quad*4 + r;
            out[(size_t)(ct>>2)*NTOT*64 + (size_t)row*64 + (ct&3)*16 + l16] = f2bf(v);
          } else {
            p[ct] += v;
          }
        }
  }
  if (LAYER==2){
    float* out = (float*)outv;
    #pragma unroll
    for (int ct=0;ct<8;ct++){
      p[ct] += __shfl_xor(p[ct], 16);
      p[ct] += __shfl_xor(p[ct], 32);
    }
    if (quad==0){
      #pragma unroll
      for (int ct=0;ct<8;ct++) colpart[wave][ct*16+l16] = p[ct];
    }
    __syncthreads();
    if (tid<128){
      float s = colpart[0][tid]+colpart[1][tid]+colpart[2][tid]+colpart[3][tid];
      out[b*128 + tid] = s * (1.f/512.f);
    }
  }
}

extern "C" void kernel_launch(void* const* d_in, const int* in_sizes, int n_in,
                              void* d_out, int out_size, void* d_ws, size_t ws_size,
                              hipStream_t stream){
  const int* node_feat = (const int*)d_in[0];
  const int* src = (const int*)d_in[1];
  const int* dst = (const int*)d_in[2];
  const float* emb = (const float*)d_in[3];
  const float* W1  = (const float*)d_in[4];
  const float* b1  = (const float*)d_in[5];
  const float* W2  = (const float*)d_in[6];
  const float* b2  = (const float*)d_in[7];

  char* ws = (char*)d_ws;
  float* out_isqrt = (float*)(ws);
  float* in_isqrt  = (float*)(ws + (size_t)NTOT*4);
  unsigned short* aggG = (unsigned short*)(ws + (size_t)NTOT*8);
  unsigned short* h1   = (unsigned short*)(ws + (size_t)NTOT*8 + (size_t)NTOT*128*2);

  (void)hipFuncSetAttribute(reinterpret_cast<const void*>(&k_agg_csr<1>),
        hipFuncAttributeMaxDynamicSharedMemorySize, LDS_L1);
  (void)hipFuncSetAttribute(reinterpret_cast<const void*>(&k_agg_csr<2>),
        hipFuncAttributeMaxDynamicSharedMemorySize, LDS_L2);

  k_deg<<<GRAPHS,256,0,stream>>>(src,dst,out_isqrt,in_isqrt);
  k_agg_csr<1><<<GRAPHS*2,512,LDS_L1,stream>>>(src,dst,node_feat,emb,
        (const unsigned short*)nullptr,out_isqrt,aggG);
  k_gemm<1><<<GRAPHS,256,0,stream>>>(aggG,W1,b1,(void*)h1);
  k_agg_csr<2><<<GRAPHS*2,512,LDS_L2,stream>>>(src,dst,node_feat,emb,h1,
        out_isqrt,aggG);
  k_gemm<2><<<GRAPHS,256,0,stream>>>(aggG,W2,b2,(void*)d_out);
}

// Round 4
// 260.990 us; speedup vs baseline: 10.7119x; 1.1403x over previous
//
#include <hip/hip_runtime.h>
#include <stdint.h>

#define GRAPHS 256
#define NPG    512
#define EPG    8192
#define NTOT   (GRAPHS*NPG)

typedef __attribute__((ext_vector_type(8))) short s16x8;
typedef __attribute__((ext_vector_type(4))) float f32x4;

__device__ __forceinline__ float bf2f(unsigned short u){
  union { unsigned int i; float f; } c; c.i = ((unsigned int)u)<<16; return c.f;
}
__device__ __forceinline__ unsigned short f2bf(float f){
  union { float f; unsigned int i; } c; c.f = f;
  unsigned int r = c.i + 0x7fffu + ((c.i>>16)&1u);   // RNE
  return (unsigned short)(r>>16);
}

// ---------- CSR build (once, shared by both layers) + out_isqrt -------------
// one block per graph; sorted entry = (ntype[src]<<9) | src
__global__ __launch_bounds__(256) void k_csr(const int* __restrict__ src,
      const int* __restrict__ dst, const int* __restrict__ ntype,
      unsigned short* __restrict__ sorted_g, int* __restrict__ start_g,
      float* __restrict__ out_isqrt){
  __shared__ int hist[NPG], cursor[NPG], co[NPG], cs[NPG+1];
  __shared__ unsigned short ntype_sh[NPG];
  __shared__ unsigned short sorted[EPG];
  const int b=blockIdx.x, tid=threadIdx.x, eb=b*EPG, nb=b*NPG;
  for (int v=tid; v<NPG; v+=256){
    hist[v]=0; co[v]=0; ntype_sh[v]=(unsigned short)ntype[nb+v];
  }
  __syncthreads();
  for (int i=tid;i<EPG;i+=256){
    atomicAdd(&hist[dst[eb+i]&(NPG-1)],1);     // int LDS atomics: native ds_add
    atomicAdd(&co[src[eb+i]&(NPG-1)],1);
  }
  __syncthreads();
  if (tid<64){                                  // wave-0 exclusive scan
    int carry=0;
    #pragma unroll
    for (int c=0;c<8;c++){
      int sc=hist[64*c+tid];
      #pragma unroll
      for (int off=1;off<64;off<<=1){ int y=__shfl_up(sc,off); if (tid>=off) sc+=y; }
      cs[64*c+tid+1]=carry+sc;
      carry+=__shfl(sc,63);
    }
    if (tid==0) cs[0]=0;
  }
  __syncthreads();
  for (int v=tid;v<NPG;v+=256) cursor[v]=cs[v];
  __syncthreads();
  for (int i=tid;i<EPG;i+=256){
    const int s=src[eb+i]&(NPG-1), d=dst[eb+i]&(NPG-1);
    const int pos=atomicAdd(&cursor[d],1);
    sorted[pos]=(unsigned short)((ntype_sh[s]<<9)|s);
  }
  __syncthreads();
  for (int i=tid;i<EPG/2;i+=256)
    ((unsigned int*)(sorted_g+(size_t)eb))[i] = ((const unsigned int*)sorted)[i];
  for (int v=tid;v<=NPG;v+=256) start_g[b*(NPG+1)+v]=cs[v];
  for (int v=tid;v<NPG;v+=256){
    int a=co[v]; if(a<1)a=1;
    out_isqrt[nb+v]=rsqrtf((float)a);
  }
}

// ---------- EW1 = emb @ W1  (64x128, bf16 out) ------------------------------
__global__ __launch_bounds__(256) void k_ew1(const float* __restrict__ emb,
      const float* __restrict__ W1, unsigned short* __restrict__ EW1){
  const int gid = blockIdx.x*256 + threadIdx.x;   // 8192 = 64*128
  const int t = gid>>7, c = gid&127;
  float acc=0.f;
  #pragma unroll 4
  for (int k=0;k<128;k++) acc += emb[t*128+k]*W1[k*128+c];
  EW1[gid]=f2bf(acc);
}

// ---------- aggregation: one block = (graph, half, 128-node chunk) ----------
// L1: feat=EW1 (indexed by type); w=out_isqrt[src]; epi: *in_isqrt +b1 relu -> h1
// L2: feat=G2 (out_isqrt pre-folded);               epi: *in_isqrt +b2 relu -> graph-mean partial
template<int LAYER>
__global__ __launch_bounds__(256) void k_agg(
      const unsigned short* __restrict__ sorted_g, const int* __restrict__ start_g,
      const unsigned short* __restrict__ feat, const float* __restrict__ out_isqrt,
      const float* __restrict__ bias, unsigned short* __restrict__ h1,
      float* __restrict__ partial){
  __shared__ unsigned short sl[EPG];      // worst-case slice (zero-risk), 16 KB
  __shared__ int sstart[129];
  __shared__ float wsc[NPG];
  __shared__ float red[16][68];
  const int bid=blockIdx.x;
  const int b=bid>>3, half=(bid>>2)&1, chunk=bid&3;
  const int v0=chunk*128, nb=b*NPG, tid=threadIdx.x;
  const int g=tid>>4, l=tid&15;
  for (int i=tid;i<129;i+=256) sstart[i]=start_g[b*(NPG+1)+v0+i];
  if (LAYER==1) for (int i=tid;i<NPG;i+=256) wsc[i]=out_isqrt[nb+i];
  __syncthreads();
  const int e0=sstart[0], cnt=sstart[128]-e0;
  const unsigned short* gs = sorted_g + (size_t)b*EPG + e0;
  for (int i=tid;i<cnt;i+=256) sl[i]=gs[i];
  float4 bz = *(const float4*)&bias[half*64 + l*4];
  __syncthreads();

  float s0=0.f,s1=0.f,s2=0.f,s3=0.f;
  for (int vi=0;vi<8;vi++){
    const int v = v0 + g*8 + vi;
    const int beg = sstart[g*8+vi]-e0, end = sstart[g*8+vi+1]-e0;
    float a0=0.f,a1=0.f,a2=0.f,a3=0.f;
    int i=beg;
    for (;i+2<=end;i+=2){
      const int ent0=sl[i], ent1=sl[i+1];
      const unsigned short *r0, *r1;
      float w0=1.f, w1=1.f;
      if (LAYER==1){
        r0 = feat + (ent0>>9)*128 + half*64 + l*4;
        r1 = feat + (ent1>>9)*128 + half*64 + l*4;
        w0 = wsc[ent0&511]; w1 = wsc[ent1&511];
      } else {
        r0 = feat + (size_t)(nb+(ent0&511))*128 + half*64 + l*4;
        r1 = feat + (size_t)(nb+(ent1&511))*128 + half*64 + l*4;
      }
      ushort4 q0 = *(const ushort4*)r0;
      ushort4 q1 = *(const ushort4*)r1;
      if (LAYER==1){
        a0 += w0*bf2f(q0.x); a1 += w0*bf2f(q0.y); a2 += w0*bf2f(q0.z); a3 += w0*bf2f(q0.w);
        a0 += w1*bf2f(q1.x); a1 += w1*bf2f(q1.y); a2 += w1*bf2f(q1.z); a3 += w1*bf2f(q1.w);
      } else {
        a0 += bf2f(q0.x); a1 += bf2f(q0.y); a2 += bf2f(q0.z); a3 += bf2f(q0.w);
        a0 += bf2f(q1.x); a1 += bf2f(q1.y); a2 += bf2f(q1.z); a3 += bf2f(q1.w);
      }
    }
    if (i<end){
      const int ent0=sl[i];
      const unsigned short* r0;
      float w0=1.f;
      if (LAYER==1){
        r0 = feat + (ent0>>9)*128 + half*64 + l*4;
        w0 = wsc[ent0&511];
      } else {
        r0 = feat + (size_t)(nb+(ent0&511))*128 + half*64 + l*4;
      }
      ushort4 q0 = *(const ushort4*)r0;
      if (LAYER==1){
        a0 += w0*bf2f(q0.x); a1 += w0*bf2f(q0.y); a2 += w0*bf2f(q0.z); a3 += w0*bf2f(q0.w);
      } else {
        a0 += bf2f(q0.x); a1 += bf2f(q0.y); a2 += bf2f(q0.z); a3 += bf2f(q0.w);
      }
    }
    int d = end-beg; if (d<1) d=1;
    const float isq = rsqrtf((float)d);
    const float o0 = fmaxf(a0*isq+bz.x,0.f), o1 = fmaxf(a1*isq+bz.y,0.f);
    const float o2 = fmaxf(a2*isq+bz.z,0.f), o3 = fmaxf(a3*isq+bz.w,0.f);
    if (LAYER==1){
      ushort4 r; r.x=f2bf(o0); r.y=f2bf(o1); r.z=f2bf(o2); r.w=f2bf(o3);
      *(ushort4*)(h1 + (size_t)(nb+v)*128 + half*64 + l*4) = r;
    } else {
      s0+=o0; s1+=o1; s2+=o2; s3+=o3;
    }
  }
  if (LAYER==2){
    red[g][l*4+0]=s0; red[g][l*4+1]=s1; red[g][l*4+2]=s2; red[g][l*4+3]=s3;
    __syncthreads();
    if (tid<64){
      float s=0.f;
      #pragma unroll
      for (int gg=0; gg<16; ++gg) s += red[gg][tid];
      partial[((b*2+half)*4+chunk)*64 + tid] = s;
    }
  }
}

// ---------- G2 = (h1 @ W2) * out_isqrt[row]  (bf16, row-major) --------------
__global__ __launch_bounds__(256) void k_gemmG2(const unsigned short* __restrict__ h1,
      const float* __restrict__ W2, const float* __restrict__ out_isqrt,
      unsigned short* __restrict__ G2){
  __shared__ __align__(16) unsigned short WT[128][136];  // WT[n][k]
  __shared__ float osc[256];
  const int blk=blockIdx.x, tid=threadIdx.x;
  for (int idx=tid; idx<128*128; idx+=256){
    const int k=idx>>7, n=idx&127;
    WT[n][k]=f2bf(W2[idx]);
  }
  if (tid<256) osc[tid]=out_isqrt[blk*256+tid];
  __syncthreads();
  const int wave=tid>>6, lane=tid&63, l16=lane&15, quad=lane>>4;
  for (int chunk=0;chunk<2;chunk++){
    const int rowbase = blk*256 + wave*64 + chunk*32;
    f32x4 acc[2][8];
    #pragma unroll
    for (int rt=0;rt<2;rt++)
      #pragma unroll
      for (int ct=0;ct<8;ct++) acc[rt][ct]=(f32x4){0.f,0.f,0.f,0.f};
    #pragma unroll
    for (int ks=0;ks<4;ks++){
      s16x8 a[2], bf[8];
      #pragma unroll
      for (int rt=0;rt<2;rt++){
        const unsigned short* ap = h1 + (size_t)(rowbase+rt*16+l16)*128 + ks*32 + quad*8;
        a[rt]=__builtin_bit_cast(s16x8, *(const uint4*)ap);
      }
      #pragma unroll
      for (int ct=0;ct<8;ct++)
        bf[ct]=__builtin_bit_cast(s16x8, *(const uint4*)&WT[ct*16+l16][ks*32+quad*8]);
      #pragma unroll
      for (int rt=0;rt<2;rt++)
        #pragma unroll
        for (int ct=0;ct<8;ct++)
          acc[rt][ct]=__builtin_amdgcn_mfma_f32_16x16x32_bf16(a[rt],bf[ct],acc[rt][ct],0,0,0);
    }
    #pragma unroll
    for (int rt=0;rt<2;rt++)
      #pragma unroll
      for (int ct=0;ct<8;ct++)
        #pragma unroll
        for (int r=0;r<4;r++){
          const int row = rowbase + rt*16 + quad*4 + r;
          const int col = ct*16 + l16;
          G2[(size_t)row*128+col] = f2bf(acc[rt][ct][r]*osc[row-blk*256]);
        }
  }
}

// ---------- final: out[b][c] = sum_chunk partial / 512 ----------------------
__global__ __launch_bounds__(256) void k_final(const float* __restrict__ partial,
      float* __restrict__ out){
  const int gid = blockIdx.x*256 + threadIdx.x;   // 32768
  const int b=gid>>7, c=gid&127, half=c>>6, cc=c&63;
  const float* p = partial + (size_t)((b*2+half)*4)*64 + cc;
  out[gid] = (p[0]+p[64]+p[128]+p[192])*(1.f/512.f);
}

extern "C" void kernel_launch(void* const* d_in, const int* in_sizes, int n_in,
                              void* d_out, int out_size, void* d_ws, size_t ws_size,
                              hipStream_t stream){
  const int* node_feat = (const int*)d_in[0];
  const int* src = (const int*)d_in[1];
  const int* dst = (const int*)d_in[2];
  const float* emb = (const float*)d_in[3];
  const float* W1  = (const float*)d_in[4];
  const float* b1  = (const float*)d_in[5];
  const float* W2  = (const float*)d_in[6];
  const float* b2  = (const float*)d_in[7];

  char* ws = (char*)d_ws;
  float* out_isqrt        = (float*)(ws);                          // 524288 B
  int* start_g            = (int*)(ws + 524288);                   // 525312 B
  unsigned short* sorted_g= (unsigned short*)(ws + 1049600);       // 4194304 B
  unsigned short* EW1     = (unsigned short*)(ws + 5243904);       // 16384 B
  unsigned short* h1      = (unsigned short*)(ws + 5260288);       // 33554432 B
  unsigned short* G2      = (unsigned short*)(ws + 38814720);      // 33554432 B
  float* partial          = (float*)(ws + 72369152);               // 524288 B

  k_csr<<<GRAPHS,256,0,stream>>>(src,dst,node_feat,sorted_g,start_g,out_isqrt);
  k_ew1<<<32,256,0,stream>>>(emb,W1,EW1);
  k_agg<1><<<GRAPHS*8,256,0,stream>>>(sorted_g,start_g,EW1,out_isqrt,b1,h1,nullptr);
  k_gemmG2<<<512,256,0,stream>>>(h1,W2,out_isqrt,G2);
  k_agg<2><<<GRAPHS*8,256,0,stream>>>(sorted_g,start_g,G2,out_isqrt,b2,nullptr,partial);
  k_final<<<128,256,0,stream>>>(partial,(float*)d_out);
}

// Round 6
// 233.068 us; speedup vs baseline: 11.9952x; 1.1198x over previous
//
#include <hip/hip_runtime.h>
#include <stdint.h>

#define GRAPHS 256
#define NPG    512
#define EPG    8192
#define NTOT   (GRAPHS*NPG)

typedef __attribute__((ext_vector_type(8))) short s16x8;
typedef __attribute__((ext_vector_type(4))) float f32x4;

__device__ __forceinline__ float bf2f(unsigned short u){
  union { unsigned int i; float f; } c; c.i = ((unsigned int)u)<<16; return c.f;
}
__device__ __forceinline__ unsigned short f2bf(float f){
  union { float f; unsigned int i; } c; c.f = f;
  unsigned int r = c.i + 0x7fffu + ((c.i>>16)&1u);   // RNE
  return (unsigned short)(r>>16);
}

// ---------- CSR build (once, shared by both layers) + out_isqrt -------------
// one block per graph; sorted entry = (ntype[src]<<9) | src
__global__ __launch_bounds__(256) void k_csr(const int* __restrict__ src,
      const int* __restrict__ dst, const int* __restrict__ ntype,
      unsigned short* __restrict__ sorted_g, int* __restrict__ start_g,
      float* __restrict__ out_isqrt){
  __shared__ int hist[NPG], cursor[NPG], co[NPG], cs[NPG+1];
  __shared__ unsigned short ntype_sh[NPG];
  __shared__ unsigned short sorted[EPG];
  const int b=blockIdx.x, tid=threadIdx.x, eb=b*EPG, nb=b*NPG;
  for (int v=tid; v<NPG; v+=256){
    hist[v]=0; co[v]=0; ntype_sh[v]=(unsigned short)ntype[nb+v];
  }
  __syncthreads();
  for (int i=tid;i<EPG;i+=256){
    atomicAdd(&hist[dst[eb+i]&(NPG-1)],1);     // int LDS atomics: native ds_add
    atomicAdd(&co[src[eb+i]&(NPG-1)],1);
  }
  __syncthreads();
  if (tid<64){                                  // wave-0 exclusive scan
    int carry=0;
    #pragma unroll
    for (int c=0;c<8;c++){
      int sc=hist[64*c+tid];
      #pragma unroll
      for (int off=1;off<64;off<<=1){ int y=__shfl_up(sc,off); if (tid>=off) sc+=y; }
      cs[64*c+tid+1]=carry+sc;
      carry+=__shfl(sc,63);
    }
    if (tid==0) cs[0]=0;
  }
  __syncthreads();
  for (int v=tid;v<NPG;v+=256) cursor[v]=cs[v];
  __syncthreads();
  for (int i=tid;i<EPG;i+=256){
    const int s=src[eb+i]&(NPG-1), d=dst[eb+i]&(NPG-1);
    const int pos=atomicAdd(&cursor[d],1);
    sorted[pos]=(unsigned short)((ntype_sh[s]<<9)|s);
  }
  __syncthreads();
  for (int i=tid;i<EPG/2;i+=256)
    ((unsigned int*)(sorted_g+(size_t)eb))[i] = ((const unsigned int*)sorted)[i];
  for (int v=tid;v<=NPG;v+=256) start_g[b*(NPG+1)+v]=cs[v];
  for (int v=tid;v<NPG;v+=256){
    int a=co[v]; if(a<1)a=1;
    out_isqrt[nb+v]=rsqrtf((float)a);
  }
}

// ---------- EW1T[c][t] = (emb @ W1)^T  (128x64, bf16) -----------------------
__global__ __launch_bounds__(256) void k_ew1(const float* __restrict__ emb,
      const float* __restrict__ W1, unsigned short* __restrict__ EW1T){
  const int gid = blockIdx.x*256 + threadIdx.x;   // 8192 = 64*128
  const int t = gid>>7, c = gid&127;
  float acc=0.f;
  #pragma unroll 4
  for (int k=0;k<128;k++) acc += emb[t*128+k]*W1[k*128+c];
  EW1T[c*64+t]=f2bf(acc);
}

// ---------- layer-1: S-histogram + MFMA(S_hi/lo @ EW1) ----------------------
// block = (graph, half: 256 dst rows), 512 thr. Writes h1T[b*128+col][row] bf16
// h1T = relu(agg*in_isqrt + b1) * out_isqrt   (osc pre-folded for layer 2)
#define A1_LDS 73232   // S f32[256][68]=69632 | wsc 2048 | sstart 1028+pad | bsh 512
__global__ __launch_bounds__(512) void k_agg1(
      const unsigned short* __restrict__ sorted_g, const int* __restrict__ start_g,
      const unsigned short* __restrict__ EW1T, const float* __restrict__ out_isqrt,
      const float* __restrict__ b1, unsigned short* __restrict__ h1T){
  extern __shared__ char smem[];
  float* S      = (float*)(smem);               // [256][68]
  float* wsc    = (float*)(smem + 69632);       // [512]
  int*   sstart = (int*)  (smem + 71680);       // [257]
  float* bsh    = (float*)(smem + 72720);       // [128]
  const int bid=blockIdx.x, b=bid>>1, half=bid&1;
  const int v0=half*256, nb=b*NPG, tid=threadIdx.x;
  for (int i=tid; i<(256*68)/4; i+=512) ((f32x4*)S)[i]=(f32x4){0.f,0.f,0.f,0.f};
  for (int i=tid; i<NPG; i+=512) wsc[i]=out_isqrt[nb+i];
  for (int i=tid; i<257; i+=512) sstart[i]=start_g[b*(NPG+1)+v0+i];
  if (tid<128) bsh[tid]=b1[tid];
  __syncthreads();
  if (tid<256){                                 // thread-per-dst scatter (no atomics)
    const int beg=sstart[tid], end=sstart[tid+1];
    float* Sd = S + tid*68;
    const unsigned short* sg = sorted_g + (size_t)b*EPG;
    for (int i=beg;i<end;++i){
      const int ent = sg[i];
      Sd[ent>>9] += wsc[ent&511];
    }
  }
  __syncthreads();
  const int wave=tid>>6, lane=tid&63, l16=lane&15, quad=lane>>4;
  f32x4 acc[2][8];
  #pragma unroll
  for (int rt=0;rt<2;rt++)
    #pragma unroll
    for (int nt=0;nt<8;nt++) acc[rt][nt]=(f32x4){0.f,0.f,0.f,0.f};
  #pragma unroll
  for (int ks=0; ks<4; ++ks){                   // ks 0,1 = hi; 2,3 = lo
    const int kc = (ks&1)*32 + quad*8;          // S column / EW1T t-index
    s16x8 a[2];
    #pragma unroll
    for (int rt=0;rt<2;rt++){
      const int m = (wave*2+rt)*16 + l16;
      const float* sp = &S[m*68 + kc];
      f32x4 va = *(const f32x4*)sp;
      f32x4 vb = *(const f32x4*)(sp+4);
      union { s16x8 v; unsigned short u[8]; } pk;
      #pragma unroll
      for (int j=0;j<8;j++){
        const float f = (j<4)? va[j] : vb[j-4];
        const unsigned short hi = f2bf(f);
        pk.u[j] = (ks<2) ? hi : f2bf(f - bf2f(hi));
      }
      a[rt]=pk.v;
    }
    s16x8 bf[8];
    #pragma unroll
    for (int nt=0;nt<8;nt++)
      bf[nt]=__builtin_bit_cast(s16x8,
          *(const uint4*)(EW1T + (size_t)(nt*16+l16)*64 + kc));
    #pragma unroll
    for (int rt=0;rt<2;rt++)
      #pragma unroll
      for (int nt=0;nt<8;nt++)
        acc[rt][nt]=__builtin_amdgcn_mfma_f32_16x16x32_bf16(a[rt],bf[nt],acc[rt][nt],0,0,0);
  }
  #pragma unroll
  for (int rt=0;rt<2;rt++){
    const int mloc = (wave*2+rt)*16 + quad*4;   // local dst row base (4 rows)
    float isq[4], os[4];
    #pragma unroll
    for (int r=0;r<4;r++){
      int d = sstart[mloc+r+1]-sstart[mloc+r]; if (d<1) d=1;
      isq[r]=rsqrtf((float)d);
      os[r]=wsc[v0+mloc+r];
    }
    #pragma unroll
    for (int nt=0;nt<8;nt++){
      const int col = nt*16+l16;
      const float bb = bsh[col];
      ushort4 st;
      float v;
      v = fmaxf(acc[rt][nt][0]*isq[0]+bb,0.f)*os[0]; st.x=f2bf(v);
      v = fmaxf(acc[rt][nt][1]*isq[1]+bb,0.f)*os[1]; st.y=f2bf(v);
      v = fmaxf(acc[rt][nt][2]*isq[2]+bb,0.f)*os[2]; st.z=f2bf(v);
      v = fmaxf(acc[rt][nt][3]*isq[3]+bb,0.f)*os[3]; st.w=f2bf(v);
      *(ushort4*)(h1T + ((size_t)(b*128+col))*512 + v0 + mloc) = st;
    }
  }
}

// ---------- layer-2: A(count-matrix) @ h1T via MFMA -------------------------
// block = (graph, 128-dst tile), 512 thr. A bf16 counts [128][520] in LDS.
// M1[row][col] = in_isqrt[row] * sum_s count[row][s] * h1T[col][s]
#define A2_LDS 133760  // A u16[128][520]=133120 | sstart 516+pad
__global__ __launch_bounds__(512) void k_agg2(
      const unsigned short* __restrict__ sorted_g, const int* __restrict__ start_g,
      const unsigned short* __restrict__ h1T, unsigned short* __restrict__ M1){
  extern __shared__ char smem[];
  unsigned short* A = (unsigned short*)smem;    // [128][520]
  int* sstart = (int*)(smem + 133120);          // [129]
  const int bid=blockIdx.x, b=bid>>2, dt=bid&3;
  const int v0=dt*128, nb=b*NPG, tid=threadIdx.x;
  for (int i=tid; i<133120/16; i+=512) ((uint4*)smem)[i]=(uint4){0u,0u,0u,0u};
  for (int i=tid; i<129; i+=512) sstart[i]=start_g[b*(NPG+1)+v0+i];
  __syncthreads();
  if (tid<128){                                 // thread-per-dst count scatter
    const int beg=sstart[tid], end=sstart[tid+1];
    unsigned short* Ad = A + tid*520;
    const unsigned short* sg = sorted_g + (size_t)b*EPG;
    for (int i=beg;i<end;++i){
      const int s = sg[i]&511;
      Ad[s] = f2bf(bf2f(Ad[s]) + 1.0f);         // exact for small int counts
    }
  }
  __syncthreads();
  const int wave=tid>>6, lane=tid&63, l16=lane&15, quad=lane>>4;
  const int mg=wave>>1, ng=wave&1;              // 2 Mtiles x 4 Ntiles per wave
  f32x4 acc[2][4];
  #pragma unroll
  for (int rt=0;rt<2;rt++)
    #pragma unroll
    for (int ct=0;ct<4;ct++) acc[rt][ct]=(f32x4){0.f,0.f,0.f,0.f};
  for (int ks=0; ks<16; ++ks){
    const int k = ks*32 + quad*8;
    s16x8 a[2], bf[4];
    #pragma unroll
    for (int rt=0;rt<2;rt++){
      const int m = (mg*2+rt)*16 + l16;
      a[rt]=__builtin_bit_cast(s16x8, *(const uint4*)(A + m*520 + k));
    }
    #pragma unroll
    for (int ct=0;ct<4;ct++){
      const int n = (ng*4+ct)*16 + l16;
      bf[ct]=__builtin_bit_cast(s16x8,
          *(const uint4*)(h1T + ((size_t)(b*128+n))*512 + k));
    }
    #pragma unroll
    for (int rt=0;rt<2;rt++)
      #pragma unroll
      for (int ct=0;ct<4;ct++)
        acc[rt][ct]=__builtin_amdgcn_mfma_f32_16x16x32_bf16(a[rt],bf[ct],acc[rt][ct],0,0,0);
  }
  #pragma unroll
  for (int rt=0;rt<2;rt++){
    const int mloc=(mg*2+rt)*16 + quad*4;
    float isq[4];
    #pragma unroll
    for (int r=0;r<4;r++){
      int d=sstart[mloc+r+1]-sstart[mloc+r]; if (d<1) d=1;
      isq[r]=rsqrtf((float)d);
    }
    #pragma unroll
    for (int ct=0;ct<4;ct++){
      const int col=(ng*4+ct)*16+l16;
      #pragma unroll
      for (int r=0;r<4;r++)
        M1[(size_t)(nb+v0+mloc+r)*128 + col] = f2bf(acc[rt][ct][r]*isq[r]);
    }
  }
}

// ---------- final GEMM: relu(M1 @ W2 + b2), fused per-graph mean -> out -----
__global__ __launch_bounds__(256) void k_gemm2(const unsigned short* __restrict__ M1,
      const float* __restrict__ W2, const float* __restrict__ b2,
      float* __restrict__ out){
  __shared__ __align__(16) unsigned short WT[128][136];  // WT[n][k]
  __shared__ float bsh[128];
  __shared__ float colpart[4][128];
  const int b=blockIdx.x, tid=threadIdx.x;
  for (int idx=tid; idx<128*128; idx+=256){
    const int k=idx>>7, n=idx&127;
    WT[n][k]=f2bf(W2[idx]);
  }
  if (tid<128) bsh[tid]=b2[tid];
  __syncthreads();
  const int wave=tid>>6, lane=tid&63, l16=lane&15, quad=lane>>4;
  float p[8];
  #pragma unroll
  for (int i=0;i<8;i++) p[i]=0.f;
  for (int chunk=0; chunk<4; ++chunk){
    const int rowbase = b*NPG + wave*128 + chunk*32;
    f32x4 acc[2][8];
    #pragma unroll
    for (int rt=0;rt<2;rt++)
      #pragma unroll
      for (int ct=0;ct<8;ct++) acc[rt][ct]=(f32x4){0.f,0.f,0.f,0.f};
    #pragma unroll
    for (int ks=0;ks<4;ks++){
      s16x8 a[2], bf[8];
      #pragma unroll
      for (int rt=0;rt<2;rt++){
        const unsigned short* ap = M1 + (size_t)(rowbase+rt*16+l16)*128 + ks*32 + quad*8;
        a[rt]=__builtin_bit_cast(s16x8, *(const uint4*)ap);
      }
      #pragma unroll
      for (int ct=0;ct<8;ct++)
        bf[ct]=__builtin_bit_cast(s16x8, *(const uint4*)&WT[ct*16+l16][ks*32+quad*8]);
      #pragma unroll
      for (int rt=0;rt<2;rt++)
        #pragma unroll
        for (int ct=0;ct<8;ct++)
          acc[rt][ct]=__builtin_amdgcn_mfma_f32_16x16x32_bf16(a[rt],bf[ct],acc[rt][ct],0,0,0);
    }
    #pragma unroll
    for (int rt=0;rt<2;rt++)
      #pragma unroll
      for (int ct=0;ct<8;ct++)
        #pragma unroll
        for (int r=0;r<4;r++){
          const int col=ct*16+l16;
          p[ct] += fmaxf(acc[rt][ct][r]+bsh[col],0.f);
        }
  }
  #pragma unroll
  for (int ct=0;ct<8;ct++){
    p[ct] += __shfl_xor(p[ct],16);
    p[ct] += __shfl_xor(p[ct],32);
  }
  if (quad==0){
    #pragma unroll
    for (int ct=0;ct<8;ct++) colpart[wave][ct*16+l16]=p[ct];
  }
  __syncthreads();
  if (tid<128){
    float s=colpart[0][tid]+colpart[1][tid]+colpart[2][tid]+colpart[3][tid];
    out[b*128+tid]=s*(1.f/512.f);
  }
}

extern "C" void kernel_launch(void* const* d_in, const int* in_sizes, int n_in,
                              void* d_out, int out_size, void* d_ws, size_t ws_size,
                              hipStream_t stream){
  const int* node_feat = (const int*)d_in[0];
  const int* src = (const int*)d_in[1];
  const int* dst = (const int*)d_in[2];
  const float* emb = (const float*)d_in[3];
  const float* W1  = (const float*)d_in[4];
  const float* b1  = (const float*)d_in[5];
  const float* W2  = (const float*)d_in[6];
  const float* b2  = (const float*)d_in[7];

  char* ws = (char*)d_ws;
  float* out_isqrt        = (float*)(ws);                          // 524288 B
  int* start_g            = (int*)(ws + 524288);                   // 525312 B
  unsigned short* sorted_g= (unsigned short*)(ws + 1049600);       // 4194304 B
  unsigned short* EW1T    = (unsigned short*)(ws + 5243904);       // 16384 B
  unsigned short* h1T     = (unsigned short*)(ws + 5260288);       // 33554432 B
  unsigned short* M1      = (unsigned short*)(ws + 38814720);      // 33554432 B

  (void)hipFuncSetAttribute(reinterpret_cast<const void*>(&k_agg1),
        hipFuncAttributeMaxDynamicSharedMemorySize, A1_LDS);
  (void)hipFuncSetAttribute(reinterpret_cast<const void*>(&k_agg2),
        hipFuncAttributeMaxDynamicSharedMemorySize, A2_LDS);

  k_csr<<<GRAPHS,256,0,stream>>>(src,dst,node_feat,sorted_g,start_g,out_isqrt);
  k_ew1<<<32,256,0,stream>>>(emb,W1,EW1T);
  k_agg1<<<GRAPHS*2,512,A1_LDS,stream>>>(sorted_g,start_g,EW1T,out_isqrt,b1,h1T);
  k_agg2<<<GRAPHS*4,512,A2_LDS,stream>>>(sorted_g,start_g,h1T,M1);
  k_gemm2<<<GRAPHS,256,0,stream>>>(M1,W2,b2,(float*)d_out);
}

// Round 7
// 203.996 us; speedup vs baseline: 13.7047x; 1.1425x over previous
//
#include <hip/hip_runtime.h>
#include <stdint.h>

#define GRAPHS 256
#define NPG    512
#define EPG    8192
#define NTOT   (GRAPHS*NPG)

typedef __attribute__((ext_vector_type(8))) short s16x8;
typedef __attribute__((ext_vector_type(4))) float f32x4;

__device__ __forceinline__ float bf2f(unsigned short u){
  union { unsigned int i; float f; } c; c.i = ((unsigned int)u)<<16; return c.f;
}
__device__ __forceinline__ unsigned short f2bf(float f){
  union { float f; unsigned int i; } c; c.f = f;
  unsigned int r = c.i + 0x7fffu + ((c.i>>16)&1u);   // RNE
  return (unsigned short)(r>>16);
}

// ---------- CSR build (once, shared by both layers) + out_isqrt -------------
// one block per graph; sorted entry = (ntype[src]<<9) | src
__global__ __launch_bounds__(512) void k_csr(const int* __restrict__ src,
      const int* __restrict__ dst, const int* __restrict__ ntype,
      unsigned short* __restrict__ sorted_g, int* __restrict__ start_g,
      float* __restrict__ out_isqrt){
  __shared__ int hist[NPG], cursor[NPG], co[NPG], cs[NPG+1];
  __shared__ unsigned short ntype_sh[NPG];
  __shared__ unsigned short sorted[EPG];
  const int b=blockIdx.x, tid=threadIdx.x, eb=b*EPG, nb=b*NPG;
  for (int v=tid; v<NPG; v+=512){
    hist[v]=0; co[v]=0; ntype_sh[v]=(unsigned short)ntype[nb+v];
  }
  __syncthreads();
  for (int i=tid;i<EPG;i+=512){
    atomicAdd(&hist[dst[eb+i]&(NPG-1)],1);     // int LDS atomics: native ds_add
    atomicAdd(&co[src[eb+i]&(NPG-1)],1);
  }
  __syncthreads();
  if (tid<64){                                  // wave-0 exclusive scan
    int carry=0;
    #pragma unroll
    for (int c=0;c<8;c++){
      int sc=hist[64*c+tid];
      #pragma unroll
      for (int off=1;off<64;off<<=1){ int y=__shfl_up(sc,off); if (tid>=off) sc+=y; }
      cs[64*c+tid+1]=carry+sc;
      carry+=__shfl(sc,63);
    }
    if (tid==0) cs[0]=0;
  }
  __syncthreads();
  for (int v=tid;v<NPG;v+=512) cursor[v]=cs[v];
  __syncthreads();
  for (int i=tid;i<EPG;i+=512){
    const int s=src[eb+i]&(NPG-1), d=dst[eb+i]&(NPG-1);
    const int pos=atomicAdd(&cursor[d],1);
    sorted[pos]=(unsigned short)((ntype_sh[s]<<9)|s);
  }
  __syncthreads();
  for (int i=tid;i<EPG/2;i+=512)
    ((unsigned int*)(sorted_g+(size_t)eb))[i] = ((const unsigned int*)sorted)[i];
  for (int v=tid;v<=NPG;v+=512) start_g[b*(NPG+1)+v]=cs[v];
  for (int v=tid;v<NPG;v+=512){
    int a=co[v]; if(a<1)a=1;
    out_isqrt[nb+v]=rsqrtf((float)a);
  }
}

// ---------- EW1T[c][t] = (emb @ W1)^T  (128x64, bf16) -----------------------
__global__ __launch_bounds__(256) void k_ew1(const float* __restrict__ emb,
      const float* __restrict__ W1, unsigned short* __restrict__ EW1T){
  const int gid = blockIdx.x*256 + threadIdx.x;   // 8192 = 64*128
  const int t = gid>>7, c = gid&127;
  float acc=0.f;
  #pragma unroll 4
  for (int k=0;k<128;k++) acc += emb[t*128+k]*W1[k*128+c];
  EW1T[c*64+t]=f2bf(acc);
}

// ---------- layer-1: S-histogram + MFMA(S_hi/lo @ EW1) ----------------------
// block = (graph, half: 256 dst rows), 512 thr. Writes h1T[b*128+col][row] bf16
// h1T = relu(agg*in_isqrt + b1) * out_isqrt   (osc pre-folded for layer 2)
#define A1_LDS 73232   // S f32[256][68]=69632 | wsc 2048 | sstart 1028+pad | bsh 512
__global__ __launch_bounds__(512) void k_agg1(
      const unsigned short* __restrict__ sorted_g, const int* __restrict__ start_g,
      const unsigned short* __restrict__ EW1T, const float* __restrict__ out_isqrt,
      const float* __restrict__ b1, unsigned short* __restrict__ h1T){
  extern __shared__ char smem[];
  float* S      = (float*)(smem);               // [256][68]
  float* wsc    = (float*)(smem + 69632);       // [512]
  int*   sstart = (int*)  (smem + 71680);       // [257]
  float* bsh    = (float*)(smem + 72720);       // [128]
  const int bid=blockIdx.x, b=bid>>1, half=bid&1;
  const int v0=half*256, nb=b*NPG, tid=threadIdx.x;
  for (int i=tid; i<(256*68)/4; i+=512) ((f32x4*)S)[i]=(f32x4){0.f,0.f,0.f,0.f};
  for (int i=tid; i<NPG; i+=512) wsc[i]=out_isqrt[nb+i];
  for (int i=tid; i<257; i+=512) sstart[i]=start_g[b*(NPG+1)+v0+i];
  if (tid<128) bsh[tid]=b1[tid];
  __syncthreads();
  if (tid<256){                                 // thread-per-dst scatter (no atomics)
    const int beg=sstart[tid], end=sstart[tid+1];
    float* Sd = S + tid*68;
    const unsigned short* sg = sorted_g + (size_t)b*EPG;
    for (int i=beg;i<end;++i){
      const int ent = sg[i];
      Sd[ent>>9] += wsc[ent&511];
    }
  }
  __syncthreads();
  const int wave=tid>>6, lane=tid&63, l16=lane&15, quad=lane>>4;
  f32x4 acc[2][8];
  #pragma unroll
  for (int rt=0;rt<2;rt++)
    #pragma unroll
    for (int nt=0;nt<8;nt++) acc[rt][nt]=(f32x4){0.f,0.f,0.f,0.f};
  #pragma unroll
  for (int ks=0; ks<4; ++ks){                   // ks 0,1 = hi; 2,3 = lo
    const int kc = (ks&1)*32 + quad*8;          // S column / EW1T t-index
    s16x8 a[2];
    #pragma unroll
    for (int rt=0;rt<2;rt++){
      const int m = (wave*2+rt)*16 + l16;
      const float* sp = &S[m*68 + kc];
      f32x4 va = *(const f32x4*)sp;
      f32x4 vb = *(const f32x4*)(sp+4);
      union { s16x8 v; unsigned short u[8]; } pk;
      #pragma unroll
      for (int j=0;j<8;j++){
        const float f = (j<4)? va[j] : vb[j-4];
        const unsigned short hi = f2bf(f);
        pk.u[j] = (ks<2) ? hi : f2bf(f - bf2f(hi));
      }
      a[rt]=pk.v;
    }
    s16x8 bf[8];
    #pragma unroll
    for (int nt=0;nt<8;nt++)
      bf[nt]=__builtin_bit_cast(s16x8,
          *(const uint4*)(EW1T + (size_t)(nt*16+l16)*64 + kc));
    #pragma unroll
    for (int rt=0;rt<2;rt++)
      #pragma unroll
      for (int nt=0;nt<8;nt++)
        acc[rt][nt]=__builtin_amdgcn_mfma_f32_16x16x32_bf16(a[rt],bf[nt],acc[rt][nt],0,0,0);
  }
  #pragma unroll
  for (int rt=0;rt<2;rt++){
    const int mloc = (wave*2+rt)*16 + quad*4;   // local dst row base (4 rows)
    float isq[4], os[4];
    #pragma unroll
    for (int r=0;r<4;r++){
      int d = sstart[mloc+r+1]-sstart[mloc+r]; if (d<1) d=1;
      isq[r]=rsqrtf((float)d);
      os[r]=wsc[v0+mloc+r];
    }
    #pragma unroll
    for (int nt=0;nt<8;nt++){
      const int col = nt*16+l16;
      const float bb = bsh[col];
      ushort4 st;
      float v;
      v = fmaxf(acc[rt][nt][0]*isq[0]+bb,0.f)*os[0]; st.x=f2bf(v);
      v = fmaxf(acc[rt][nt][1]*isq[1]+bb,0.f)*os[1]; st.y=f2bf(v);
      v = fmaxf(acc[rt][nt][2]*isq[2]+bb,0.f)*os[2]; st.z=f2bf(v);
      v = fmaxf(acc[rt][nt][3]*isq[3]+bb,0.f)*os[3]; st.w=f2bf(v);
      *(ushort4*)(h1T + ((size_t)(b*128+col))*512 + v0 + mloc) = st;
    }
  }
}

// ---------- layer-2: A(u8 count-matrix) @ h1T via MFMA ----------------------
// block = (graph, 128-dst tile). A u8 [128][520] in LDS (67 KB -> 2 blocks/CU).
// Parallel scatter: 4 threads/dst, u32 LDS atomics on packed u8 lanes.
// bid swizzle: the 4 dt-blocks of a graph share bid%8 -> same XCD L2.
// M1[row][col] = in_isqrt[row] * sum_s count[row][s] * h1T[col][s]
#define A2_LDS 67080   // A u8[128][520]=66560 | sstart[129]=516 + pad
__global__ __launch_bounds__(512) void k_agg2(
      const unsigned short* __restrict__ sorted_g, const int* __restrict__ start_g,
      const unsigned short* __restrict__ h1T, unsigned short* __restrict__ M1){
  extern __shared__ char smem[];
  unsigned char* A = (unsigned char*)smem;      // [128][520]
  unsigned int* A32 = (unsigned int*)smem;
  int* sstart = (int*)(smem + 66560);           // [129]
  const int bid=blockIdx.x;
  const int b  = ((bid>>5)<<3) | (bid&7);       // graph
  const int dt = (bid>>3)&3;                    // dst tile
  const int v0=dt*128, nb=b*NPG, tid=threadIdx.x;
  for (int i=tid; i<66560/16; i+=512) ((uint4*)smem)[i]=(uint4){0u,0u,0u,0u};
  for (int i=tid; i<129; i+=512) sstart[i]=start_g[b*(NPG+1)+v0+i];
  __syncthreads();
  {                                             // parallel count scatter
    const int d = tid>>2, q = tid&3;
    const int beg=sstart[d], end=sstart[d+1], len=end-beg;
    const int qb = beg + ((len*q)>>2), qe = beg + ((len*(q+1))>>2);
    const unsigned short* sg = sorted_g + (size_t)b*EPG;
    const int rowbase = d*130;
    for (int i=qb;i<qe;++i){
      const int s = sg[i]&511;
      atomicAdd(&A32[rowbase + (s>>2)], 1u<<((s&3)*8));
    }
  }
  __syncthreads();
  const int wave=tid>>6, lane=tid&63, l16=lane&15, quad=lane>>4;
  const int mg=wave>>1, ng=wave&1;              // 2 Mtiles x 4 Ntiles per wave
  f32x4 acc[2][4];
  #pragma unroll
  for (int rt=0;rt<2;rt++)
    #pragma unroll
    for (int ct=0;ct<4;ct++) acc[rt][ct]=(f32x4){0.f,0.f,0.f,0.f};
  for (int ks=0; ks<16; ++ks){
    const int k = ks*32 + quad*8;
    s16x8 a[2], bf[4];
    #pragma unroll
    for (int rt=0;rt<2;rt++){
      const int m = (mg*2+rt)*16 + l16;
      const unsigned char* Ar = A + m*520 + k;
      const unsigned int w0 = *(const unsigned int*)(Ar);
      const unsigned int w1 = *(const unsigned int*)(Ar+4);
      union { s16x8 v; unsigned short u[8]; } pk;
      #pragma unroll
      for (int j=0;j<4;j++){
        const float f0 = (float)((w0>>(8*j))&0xffu);   // v_cvt_f32_ubyte, exact
        const float f1 = (float)((w1>>(8*j))&0xffu);
        pk.u[j]   = (unsigned short)(__builtin_bit_cast(unsigned int, f0)>>16);
        pk.u[j+4] = (unsigned short)(__builtin_bit_cast(unsigned int, f1)>>16);
      }
      a[rt]=pk.v;
    }
    #pragma unroll
    for (int ct=0;ct<4;ct++){
      const int n = (ng*4+ct)*16 + l16;
      bf[ct]=__builtin_bit_cast(s16x8,
          *(const uint4*)(h1T + ((size_t)(b*128+n))*512 + k));
    }
    #pragma unroll
    for (int rt=0;rt<2;rt++)
      #pragma unroll
      for (int ct=0;ct<4;ct++)
        acc[rt][ct]=__builtin_amdgcn_mfma_f32_16x16x32_bf16(a[rt],bf[ct],acc[rt][ct],0,0,0);
  }
  #pragma unroll
  for (int rt=0;rt<2;rt++){
    const int mloc=(mg*2+rt)*16 + quad*4;
    float isq[4];
    #pragma unroll
    for (int r=0;r<4;r++){
      int d=sstart[mloc+r+1]-sstart[mloc+r]; if (d<1) d=1;
      isq[r]=rsqrtf((float)d);
    }
    #pragma unroll
    for (int ct=0;ct<4;ct++){
      const int col=(ng*4+ct)*16+l16;
      #pragma unroll
      for (int r=0;r<4;r++)
        M1[(size_t)(nb+v0+mloc+r)*128 + col] = f2bf(acc[rt][ct][r]*isq[r]);
    }
  }
}

// ---------- final GEMM: relu(M1 @ W2 + b2), fused per-graph mean -> out -----
__global__ __launch_bounds__(512) void k_gemm2(const unsigned short* __restrict__ M1,
      const float* __restrict__ W2, const float* __restrict__ b2,
      float* __restrict__ out){
  __shared__ __align__(16) unsigned short WT[128][136];  // WT[n][k]
  __shared__ float bsh[128];
  __shared__ float colpart[8][128];
  const int b=blockIdx.x, tid=threadIdx.x;
  for (int idx=tid; idx<128*128; idx+=512){
    const int k=idx>>7, n=idx&127;
    WT[n][k]=f2bf(W2[idx]);
  }
  if (tid<128) bsh[tid]=b2[tid];
  __syncthreads();
  const int wave=tid>>6, lane=tid&63, l16=lane&15, quad=lane>>4;
  float p[8];
  #pragma unroll
  for (int i=0;i<8;i++) p[i]=0.f;
  for (int chunk=0; chunk<2; ++chunk){
    const int rowbase = b*NPG + wave*64 + chunk*32;
    f32x4 acc[2][8];
    #pragma unroll
    for (int rt=0;rt<2;rt++)
      #pragma unroll
      for (int ct=0;ct<8;ct++) acc[rt][ct]=(f32x4){0.f,0.f,0.f,0.f};
    #pragma unroll
    for (int ks=0;ks<4;ks++){
      s16x8 a[2], bf[8];
      #pragma unroll
      for (int rt=0;rt<2;rt++){
        const unsigned short* ap = M1 + (size_t)(rowbase+rt*16+l16)*128 + ks*32 + quad*8;
        a[rt]=__builtin_bit_cast(s16x8, *(const uint4*)ap);
      }
      #pragma unroll
      for (int ct=0;ct<8;ct++)
        bf[ct]=__builtin_bit_cast(s16x8, *(const uint4*)&WT[ct*16+l16][ks*32+quad*8]);
      #pragma unroll
      for (int rt=0;rt<2;rt++)
        #pragma unroll
        for (int ct=0;ct<8;ct++)
          acc[rt][ct]=__builtin_amdgcn_mfma_f32_16x16x32_bf16(a[rt],bf[ct],acc[rt][ct],0,0,0);
    }
    #pragma unroll
    for (int rt=0;rt<2;rt++)
      #pragma unroll
      for (int ct=0;ct<8;ct++)
        #pragma unroll
        for (int r=0;r<4;r++){
          const int col=ct*16+l16;
          p[ct] += fmaxf(acc[rt][ct][r]+bsh[col],0.f);
        }
  }
  #pragma unroll
  for (int ct=0;ct<8;ct++){
    p[ct] += __shfl_xor(p[ct],16);
    p[ct] += __shfl_xor(p[ct],32);
  }
  if (quad==0){
    #pragma unroll
    for (int ct=0;ct<8;ct++) colpart[wave][ct*16+l16]=p[ct];
  }
  __syncthreads();
  if (tid<128){
    float s=0.f;
    #pragma unroll
    for (int w=0;w<8;w++) s+=colpart[w][tid];
    out[b*128+tid]=s*(1.f/512.f);
  }
}

extern "C" void kernel_launch(void* const* d_in, const int* in_sizes, int n_in,
                              void* d_out, int out_size, void* d_ws, size_t ws_size,
                              hipStream_t stream){
  const int* node_feat = (const int*)d_in[0];
  const int* src = (const int*)d_in[1];
  const int* dst = (const int*)d_in[2];
  const float* emb = (const float*)d_in[3];
  const float* W1  = (const float*)d_in[4];
  const float* b1  = (const float*)d_in[5];
  const float* W2  = (const float*)d_in[6];
  const float* b2  = (const float*)d_in[7];

  char* ws = (char*)d_ws;
  float* out_isqrt        = (float*)(ws);                          // 524288 B
  int* start_g            = (int*)(ws + 524288);                   // 525312 B
  unsigned short* sorted_g= (unsigned short*)(ws + 1049600);       // 4194304 B
  unsigned short* EW1T    = (unsigned short*)(ws + 5243904);       // 16384 B
  unsigned short* h1T     = (unsigned short*)(ws + 5260288);       // 33554432 B
  unsigned short* M1      = (unsigned short*)(ws + 38814720);      // 33554432 B

  (void)hipFuncSetAttribute(reinterpret_cast<const void*>(&k_agg1),
        hipFuncAttributeMaxDynamicSharedMemorySize, A1_LDS);
  (void)hipFuncSetAttribute(reinterpret_cast<const void*>(&k_agg2),
        hipFuncAttributeMaxDynamicSharedMemorySize, A2_LDS);

  k_csr<<<GRAPHS,512,0,stream>>>(src,dst,node_feat,sorted_g,start_g,out_isqrt);
  k_ew1<<<32,256,0,stream>>>(emb,W1,EW1T);
  k_agg1<<<GRAPHS*2,512,A1_LDS,stream>>>(sorted_g,start_g,EW1T,out_isqrt,b1,h1T);
  k_agg2<<<GRAPHS*4,512,A2_LDS,stream>>>(sorted_g,start_g,h1T,M1);
  k_gemm2<<<GRAPHS,512,0,stream>>>(M1,W2,b2,(float*)d_out);
}